// Round 1
// 408.255 us; speedup vs baseline: 1.0707x; 1.0707x over previous
//
#include <hip/hip_runtime.h>

// Problem constants (fixed by the reference): B=256, N=2048, D=128, ANCHOR=0
#define B_SZ    256
#define N_NODES 2048
#define D_DIM   128
#define NROW_TOT (B_SZ * N_NODES)   // 524288

typedef __attribute__((ext_vector_type(8))) short short8;   // 8 bf16 = 4 VGPRs (MFMA A/B frag)
typedef __attribute__((ext_vector_type(4))) float f32x4;    // MFMA C/D frag

// ---- workspace layout (bytes) ----
#define WS_W1BF   0          // 128*256 bf16 = 65536
#define WS_COUNT  65536      // 256 * 4 (doubles as cursor and final count)
#define WS_ACC    66560      // 256*128*4 = 131072
#define WS_P      197632     // 256 * CAP * 4 = 4194304
#define CAP       4096       // bucket capacity; binomial(524288,1/256) mean 2047, sd ~45
#define WS_NEEDED (WS_P + B_SZ * CAP * 4)

// RNE fp32->bf16 pack of two floats into one uint (lo = first)
__device__ __forceinline__ unsigned pk2(float x, float y) {
    unsigned a = __float_as_uint(x), b = __float_as_uint(y);
    a += 0x7fffu + ((a >> 16) & 1u);
    b += 0x7fffu + ((b >> 16) & 1u);
    return (a >> 16) | (b & 0xffff0000u);
}

// ---- fused prep: blocks 0..63 convert W1 -> bf16; blocks 64..575 bucket-scatter ----
// Scatter: per-block LDS histogram -> one global atomicAdd per segment to reserve a
// slot range in the fixed-capacity bucket, then direct writes. No scan pass needed.
__global__ void k_prep(const float* __restrict__ W1, unsigned* __restrict__ w1bf,
                       const int* __restrict__ bidx, int* __restrict__ count,
                       int* __restrict__ P) {
    if (blockIdx.x < 64) {
        int i = blockIdx.x * 256 + threadIdx.x;           // 16384 float2 pairs
        float2 f = ((const float2*)W1)[i];
        w1bf[i] = pk2(f.x, f.y);
        return;
    }
    __shared__ int lh[256];
    __shared__ int sbase[256];
    int blk = blockIdx.x - 64;                            // 0..511
    int t = threadIdx.x;
    lh[t] = 0;
    __syncthreads();
    int base = blk * 1024 + t * 4;
    int4 v = ((const int4*)bidx)[blk * 256 + t];
    int p0 = -1, p1 = -1, p2 = -1, p3 = -1;
    if (((base + 0) & 2047) != 0) p0 = atomicAdd(&lh[v.x], 1);   // skip anchors (row%2048==0)
    if (((base + 1) & 2047) != 0) p1 = atomicAdd(&lh[v.y], 1);
    if (((base + 2) & 2047) != 0) p2 = atomicAdd(&lh[v.z], 1);
    if (((base + 3) & 2047) != 0) p3 = atomicAdd(&lh[v.w], 1);
    __syncthreads();
    if (lh[t]) sbase[t] = atomicAdd(&count[t], lh[t]);
    __syncthreads();
    if (p0 >= 0) P[v.x * CAP + sbase[v.x] + p0] = base + 0;
    if (p1 >= 0) P[v.y * CAP + sbase[v.y] + p1] = base + 1;
    if (p2 >= 0) P[v.z * CAP + sbase[v.z] + p2] = base + 2;
    if (p3 >= 0) P[v.w * CAP + sbase[v.w] + p3] = base + 3;
}

// ---- main: per-segment gather + bf16 MFMA GEMM (K=256: [target|emb]) + row-sum ----
// targets (anchor rows, 256 x 128) preloaded ONCE to LDS in bf16 (XOR-swizzled);
// per-chunk staging is emb-only, double-buffered, ONE barrier/chunk, with the
// next chunk's gather issued during the current chunk's MFMA (latency hidden).
#define CHUNK   64
#define ESTRIDE 272   // 256B (128 bf16) + 4B batch-id + pad; 272/4 % 32 == 4 -> 2-way max

__global__ __launch_bounds__(1024) void k_main(
    const float* __restrict__ embs, const float* __restrict__ b1,
    const short* __restrict__ w1bf, const int* __restrict__ P,
    const int* __restrict__ count, float* __restrict__ ACC)
{
    __shared__ char  tgt[256 * 256];            // 65536 B: all 256 target rows, bf16, swizzled
    __shared__ char  estage[2][CHUNK * ESTRIDE];// 2 * 17408 B
    __shared__ float segacc[D_DIM];

    int tid = threadIdx.x;
    int s   = blockIdx.x;
    int cnt = count[s];
    const int pbase = s * CAP;

    if (tid < D_DIM) segacc[tid] = 0.f;

    // -------- preload 256 target rows -> tgt (bf16, byte ^= (row&7)<<4) --------
#pragma unroll
    for (int it = 0; it < 4; it++) {
        int task = it * 1024 + tid;             // 4096 tasks: 256 rows x 16 slots
        int tr = task >> 4;                     // target row (= batch)
        int p  = task & 15;                     // 16B slot within row
        const float4* src = (const float4*)(embs + ((size_t)(tr << 11)) * D_DIM) + p * 2;
        float4 g0 = src[0], g1 = src[1];
        uint4 w = make_uint4(pk2(g0.x, g0.y), pk2(g0.z, g0.w),
                             pk2(g1.x, g1.y), pk2(g1.z, g1.w));
        *(uint4*)(tgt + ((tr * 256 + p * 16) ^ ((tr & 7) << 4))) = w;
    }

    int lane = tid & 63;
    int wid  = tid >> 6;       // 0..15
    int rt   = wid & 3;        // row-tile (16 rows each)
    int cg   = wid >> 2;       // col-group (32 cols each)
    int q    = lane >> 4;      // quad 0..3
    int i15  = lane & 15;

    // B fragments: W1[n][k], n = cg*32 + ct*16 + i15, k = kt*32 + q*8 .. +8
    short8 bfrag[8][2];
#pragma unroll
    for (int kt = 0; kt < 8; kt++)
#pragma unroll
        for (int ct = 0; ct < 2; ct++) {
            int n = cg * 32 + ct * 16 + i15;
            bfrag[kt][ct] = *(const short8*)(w1bf + n * 256 + kt * 32 + q * 8);
        }
    float b1c0 = b1[cg * 32 + i15];
    float b1c1 = b1[cg * 32 + 16 + i15];
    float asum0 = 0.f, asum1 = 0.f;

    // staging role: 512 threads, 8 per row (64B fp32 each -> 32B bf16)
    int srow = tid >> 3;       // 0..63 (valid when tid<512)
    int part = tid & 7;
    bool stager = tid < 512;

    int nchunk = (cnt + CHUNK - 1) >> 6;

    // pipeline registers
    float4 f0, f1, f2, f3;
    int bcur = 0, ridx_next = 0;

    if (nchunk > 0 && stager) {
        int gr = pbase + (srow < cnt ? srow : cnt - 1);
        int r0 = P[gr];
        bcur = r0 >> 11;
        const float4* src = (const float4*)(embs + (size_t)r0 * D_DIM) + part * 4;
        f0 = src[0]; f1 = src[1]; f2 = src[2]; f3 = src[3];
        if (nchunk > 1) {
            int rl = CHUNK + srow;
            ridx_next = P[pbase + (rl < cnt ? rl : cnt - 1)];
        }
    }
    __syncthreads();   // segacc zero + tgt visible even when nchunk==0

    for (int c = 0; c < nchunk; c++) {
        char* wb = estage[c & 1];
        // ---- write staged regs (loaded last iteration) into buffer ----
        if (stager) {
            uint4 wa = make_uint4(pk2(f0.x, f0.y), pk2(f0.z, f0.w),
                                  pk2(f1.x, f1.y), pk2(f1.z, f1.w));
            uint4 wbv = make_uint4(pk2(f2.x, f2.y), pk2(f2.z, f2.w),
                                   pk2(f3.x, f3.y), pk2(f3.z, f3.w));
            uint4* dst = (uint4*)(wb + srow * ESTRIDE + part * 32);
            dst[0] = wa; dst[1] = wbv;
            if (part == 0) *(int*)(wb + srow * ESTRIDE + 256) = bcur;
        }
        __syncthreads();   // single barrier per chunk (double-buffered)

        // ---- issue next chunk's gather; lands during MFMA below ----
        if (stager && c + 1 < nchunk) {
            int r = ridx_next;
            bcur = r >> 11;
            const float4* src = (const float4*)(embs + (size_t)r * D_DIM) + part * 4;
            f0 = src[0]; f1 = src[1]; f2 = src[2]; f3 = src[3];
            if (c + 2 < nchunk) {
                int rl = (c + 2) * CHUNK + srow;
                ridx_next = P[pbase + (rl < cnt ? rl : cnt - 1)];
            }
        }

        // ---- MFMA: 16 rows x 32 cols per wave, K=256 = [target(128) | emb(128)] ----
        f32x4 m0 = {0.f, 0.f, 0.f, 0.f}, m1 = {0.f, 0.f, 0.f, 0.f};
        int row = rt * 16 + i15;
        int b = *(const int*)(wb + row * ESTRIDE + 256);
        unsigned sw = ((unsigned)(b & 7)) << 4;
        unsigned tb = ((unsigned)b << 8) + (unsigned)(q * 16);
#pragma unroll
        for (int kt = 0; kt < 4; kt++) {       // K 0..127: target from preloaded LDS
            short8 a = *(const short8*)(tgt + ((tb + kt * 64) ^ sw));
            m0 = __builtin_amdgcn_mfma_f32_16x16x32_bf16(a, bfrag[kt][0], m0, 0, 0, 0);
            m1 = __builtin_amdgcn_mfma_f32_16x16x32_bf16(a, bfrag[kt][1], m1, 0, 0, 0);
        }
        const char* ar = wb + row * ESTRIDE + q * 16;
#pragma unroll
        for (int kt = 0; kt < 4; kt++) {       // K 128..255: emb from staged buffer
            short8 a = *(const short8*)(ar + kt * 64);
            m0 = __builtin_amdgcn_mfma_f32_16x16x32_bf16(a, bfrag[kt + 4][0], m0, 0, 0, 0);
            m1 = __builtin_amdgcn_mfma_f32_16x16x32_bf16(a, bfrag[kt + 4][1], m1, 0, 0, 0);
        }
        // epilogue: h = relu(acc + b1), sum over valid rows (D row = q*4+j)
        int rbase = c * 64 + rt * 16 + q * 4;
#pragma unroll
        for (int j = 0; j < 4; j++) {
            if (rbase + j < cnt) {
                asum0 += fmaxf(m0[j] + b1c0, 0.f);
                asum1 += fmaxf(m1[j] + b1c1, 0.f);
            }
        }
        // no trailing barrier: next iteration writes the OTHER buffer, and its
        // top barrier orders all of this iteration's reads before any overwrite.
    }

    // reduce across quads (same col in lanes l, l^16, l^32, l^48)
    asum0 += __shfl_xor(asum0, 16, 64);
    asum0 += __shfl_xor(asum0, 32, 64);
    asum1 += __shfl_xor(asum1, 16, 64);
    asum1 += __shfl_xor(asum1, 32, 64);
    if (lane < 16) {
        atomicAdd(&segacc[cg * 32 + lane],      asum0);
        atomicAdd(&segacc[cg * 32 + 16 + lane], asum1);
    }
    __syncthreads();
    if (tid < D_DIM) ACC[s * D_DIM + tid] = segacc[tid];
}

// ---- out[s][d] = sum_k ACC[s][k] * W2[d][k] + cnt[s]*b2[d] ----
__global__ void k_out(const float* __restrict__ ACC, const float* __restrict__ W2,
                      const float* __restrict__ b2, const int* __restrict__ count,
                      float* __restrict__ out) {
    __shared__ float a[D_DIM];
    int s = blockIdx.x, d = threadIdx.x;
    a[d] = ACC[s * D_DIM + d];
    __syncthreads();
    float sum = (float)count[s] * b2[d];
    const float4* w = (const float4*)(W2 + d * D_DIM);
#pragma unroll
    for (int k = 0; k < 32; k++) {
        float4 wv = w[k];
        sum += a[4 * k + 0] * wv.x + a[4 * k + 1] * wv.y
             + a[4 * k + 2] * wv.z + a[4 * k + 3] * wv.w;
    }
    out[s * D_DIM + d] = sum;
}

extern "C" void kernel_launch(void* const* d_in, const int* in_sizes, int n_in,
                              void* d_out, int out_size, void* d_ws, size_t ws_size,
                              hipStream_t stream) {
    const float* embs = (const float*)d_in[0];
    const float* W1   = (const float*)d_in[1];
    const float* b1   = (const float*)d_in[2];
    const float* W2   = (const float*)d_in[3];
    const float* b2   = (const float*)d_in[4];
    const int*   bidx = (const int*)d_in[5];

    char* ws = (char*)d_ws;
    unsigned* w1bf_u = (unsigned*)(ws + WS_W1BF);
    short*    w1bf   = (short*)(ws + WS_W1BF);
    int*   count  = (int*)(ws + WS_COUNT);
    float* ACC    = (float*)(ws + WS_ACC);
    int*   P      = (int*)(ws + WS_P);

    hipMemsetAsync(count, 0, 256 * sizeof(int), stream);
    k_prep<<<576, 256, 0, stream>>>(W1, w1bf_u, bidx, count, P);
    k_main<<<256, 1024, 0, stream>>>(embs, b1, w1bf, P, count, ACC);
    k_out<<<256, 128, 0, stream>>>(ACC, W2, b2, count, (float*)d_out);
}

// Round 2
// 403.446 us; speedup vs baseline: 1.0835x; 1.0119x over previous
//
#include <hip/hip_runtime.h>

// Problem constants (fixed by the reference): B=256, N=2048, D=128, ANCHOR=0
#define B_SZ    256
#define N_NODES 2048
#define D_DIM   128
#define NROW_TOT (B_SZ * N_NODES)   // 524288

typedef __attribute__((ext_vector_type(8))) short short8;   // 8 bf16 = 4 VGPRs (MFMA A/B frag)
typedef __attribute__((ext_vector_type(4))) float f32x4;    // MFMA C/D frag

// ---- workspace layout (bytes) ----
#define WS_W1BF   0          // 128*256 bf16 = 65536
#define WS_COUNT  65536      // 256 * 4
#define WS_T      66560      // 256*128*4 = 131072  (T[b][d] = target_b . W1[d,0:128] + b1[d])
#define WS_ACC    197632     // 512*128*4 = 262144  (per half-block partials)
#define WS_P      459776     // 256 * CAP * 4 = 4194304
#define CAP       4096       // bucket capacity; binomial(524288,1/256) mean 2047, sd ~45
#define WS_NEEDED (WS_P + B_SZ * CAP * 4)

// RNE fp32->bf16 pack of two floats into one uint (lo = first)
__device__ __forceinline__ unsigned pk2(float x, float y) {
    unsigned a = __float_as_uint(x), b = __float_as_uint(y);
    a += 0x7fffu + ((a >> 16) & 1u);
    b += 0x7fffu + ((b >> 16) & 1u);
    return (a >> 16) | (b & 0xffff0000u);
}

// ---- fused prep ----
// blocks   0..63 : W1 -> bf16 (full 128x256; k_main uses k=128..255 half)
// blocks  64..575: bucket-scatter of row ids by batch_idx (capacity buckets, no scan)
// blocks 576..831: T[b][d] = dot(target_b, W1[d][0:128]) + b1[d]   (fp32, 256x128)
__global__ void k_prep(const float* __restrict__ W1, unsigned* __restrict__ w1bf,
                       const int* __restrict__ bidx, int* __restrict__ count,
                       int* __restrict__ P, const float* __restrict__ embs,
                       const float* __restrict__ b1, float* __restrict__ T) {
    int t = threadIdx.x;
    if (blockIdx.x < 64) {
        int i = blockIdx.x * 256 + t;                     // 16384 float2 pairs
        float2 f = ((const float2*)W1)[i];
        w1bf[i] = pk2(f.x, f.y);
        return;
    }
    if (blockIdx.x >= 576) {
        int tb = blockIdx.x - 576;                        // batch 0..255
        __shared__ float trow[128];
        if (t < 128) trow[t] = embs[(size_t)(tb << 11) * D_DIM + t];
        __syncthreads();
        if (t < 128) {
            const float4* w = (const float4*)(W1 + t * 256);   // W1[d][k], k<128 half
            float s = 0.f;
#pragma unroll
            for (int k = 0; k < 32; k++) {
                float4 wv = w[k];
                s += trow[4 * k + 0] * wv.x + trow[4 * k + 1] * wv.y
                   + trow[4 * k + 2] * wv.z + trow[4 * k + 3] * wv.w;
            }
            T[tb * 128 + t] = s + b1[t];
        }
        return;
    }
    __shared__ int lh[256];
    __shared__ int sbase[256];
    int blk = blockIdx.x - 64;                            // 0..511
    lh[t] = 0;
    __syncthreads();
    int base = blk * 1024 + t * 4;
    int4 v = ((const int4*)bidx)[blk * 256 + t];
    int p0 = -1, p1 = -1, p2 = -1, p3 = -1;
    if (((base + 0) & 2047) != 0) p0 = atomicAdd(&lh[v.x], 1);   // skip anchors (row%2048==0)
    if (((base + 1) & 2047) != 0) p1 = atomicAdd(&lh[v.y], 1);
    if (((base + 2) & 2047) != 0) p2 = atomicAdd(&lh[v.z], 1);
    if (((base + 3) & 2047) != 0) p3 = atomicAdd(&lh[v.w], 1);
    __syncthreads();
    if (lh[t]) sbase[t] = atomicAdd(&count[t], lh[t]);
    __syncthreads();
    if (p0 >= 0) P[v.x * CAP + sbase[v.x] + p0] = base + 0;
    if (p1 >= 0) P[v.y * CAP + sbase[v.y] + p1] = base + 1;
    if (p2 >= 0) P[v.z * CAP + sbase[v.z] + p2] = base + 2;
    if (p3 >= 0) P[v.w * CAP + sbase[v.w] + p3] = base + 3;
}

// ---- main: per-segment gather + bf16 MFMA (K=128, emb only) + T add + row-sum ----
// 512 blocks (2 per segment, alternate chunks), 512 threads, 2 blocks/CU co-resident.
// Per chunk: stage 64 emb rows bf16 (double-buffered, ONE barrier), prefetch next
// chunk's gather + this chunk's T rows under the MFMA phase.
#define CHUNK   64
#define ESTRIDE 272   // 256B (128 bf16) + 16B pad -> 2-way max on b128 access

__global__ __launch_bounds__(512, 4) void k_main(
    const float* __restrict__ embs, const float* __restrict__ Tm,
    const short* __restrict__ w1bf, const int* __restrict__ P,
    const int* __restrict__ count, float* __restrict__ ACC)
{
    __shared__ __align__(16) char estage[2][CHUNK * ESTRIDE];   // 2 * 17408 B
    __shared__ int   bidarr[2][64];
    __shared__ float segacc[D_DIM];

    int tid  = threadIdx.x;
    int g    = blockIdx.x;
    int s    = g >> 1;
    int half = g & 1;
    int cnt  = count[s];
    const int pbase = s * CAP;

    if (tid < D_DIM) segacc[tid] = 0.f;

    int lane = tid & 63;
    int wid  = tid >> 6;       // 0..7
    int rt   = wid & 1;        // row-tile pair (32 rows)
    int cg   = wid >> 1;       // col-group (32 cols)
    int q    = lane >> 4;      // quad 0..3
    int i15  = lane & 15;

    // B fragments: W1[n][k], n = cg*32 + ct*16 + i15, k = 128 + kt*32 + q*8
    short8 bfrag[4][2];
#pragma unroll
    for (int kt = 0; kt < 4; kt++)
#pragma unroll
        for (int ct = 0; ct < 2; ct++) {
            int n = cg * 32 + ct * 16 + i15;
            bfrag[kt][ct] = *(const short8*)(w1bf + n * 256 + 128 + kt * 32 + q * 8);
        }

    // staging role: all 512 threads, 8 per row (64B fp32 -> 32B bf16)
    int srow = tid >> 3;       // 0..63
    int part = tid & 7;

    int nct = (cnt + CHUNK - 1) >> 6;                       // total chunks
    int myn = (nct > half) ? ((nct - half + 1) >> 1) : 0;   // my chunks: half, half+2, ...

    // pipeline registers
    float4 f0, f1, f2, f3;
    int bcur = 0, ridx_next = 0;

    if (myn > 0) {
        int rl = half * 64 + srow;
        int r0 = P[pbase + (rl < cnt ? rl : cnt - 1)];
        bcur = r0 >> 11;
        const float4* src = (const float4*)(embs + (size_t)r0 * D_DIM) + part * 4;
        f0 = src[0]; f1 = src[1]; f2 = src[2]; f3 = src[3];
        if (myn > 1) {
            int rl2 = (half + 2) * 64 + srow;
            ridx_next = P[pbase + (rl2 < cnt ? rl2 : cnt - 1)];
        }
    }
    __syncthreads();   // segacc zero visible even when myn==0

    float asum0 = 0.f, asum1 = 0.f;

    for (int i = 0; i < myn; i++) {
        int c = half + 2 * i;
        char* wb = estage[i & 1];
        // ---- write staged regs (loaded last iteration) ----
        {
            uint4 wa = make_uint4(pk2(f0.x, f0.y), pk2(f0.z, f0.w),
                                  pk2(f1.x, f1.y), pk2(f1.z, f1.w));
            uint4 wv = make_uint4(pk2(f2.x, f2.y), pk2(f2.z, f2.w),
                                  pk2(f3.x, f3.y), pk2(f3.z, f3.w));
            uint4* dst = (uint4*)(wb + srow * ESTRIDE + part * 32);
            dst[0] = wa; dst[1] = wv;
            if (part == 0) bidarr[i & 1][srow] = bcur;
        }
        __syncthreads();   // single barrier per chunk (double-buffered)

        // ---- prefetch T rows for my C-fragment rows (L2-hot), hidden by MFMA ----
        int4 bh0 = *(const int4*)&bidarr[i & 1][rt * 32 + q * 4];        // h=0 rows
        int4 bh1 = *(const int4*)&bidarr[i & 1][rt * 32 + 16 + q * 4];   // h=1 rows
        int c0 = cg * 32 + i15;
        float tv0[4][2], tv1[4][2];
#pragma unroll
        for (int j = 0; j < 4; j++) {
            int b0 = (&bh0.x)[j], b1i = (&bh1.x)[j];
            tv0[j][0] = Tm[b0 * 128 + c0];  tv0[j][1] = Tm[b0 * 128 + c0 + 16];
            tv1[j][0] = Tm[b1i * 128 + c0]; tv1[j][1] = Tm[b1i * 128 + c0 + 16];
        }

        // ---- issue next chunk's gather; lands during MFMA below ----
        if (i + 1 < myn) {
            int r = ridx_next;
            bcur = r >> 11;
            const float4* src = (const float4*)(embs + (size_t)r * D_DIM) + part * 4;
            f0 = src[0]; f1 = src[1]; f2 = src[2]; f3 = src[3];
            if (i + 2 < myn) {
                int rl = (c + 4) * 64 + srow;
                ridx_next = P[pbase + (rl < cnt ? rl : cnt - 1)];
            }
        }

        // ---- MFMA: 32 rows x 32 cols per wave, K=128 (emb half only) ----
        f32x4 m00 = {0,0,0,0}, m01 = {0,0,0,0}, m10 = {0,0,0,0}, m11 = {0,0,0,0};
        const char* ar0 = wb + (rt * 32 + i15) * ESTRIDE + q * 16;
        const char* ar1 = ar0 + 16 * ESTRIDE;
#pragma unroll
        for (int kt = 0; kt < 4; kt++) {
            short8 a0 = *(const short8*)(ar0 + kt * 64);
            short8 a1 = *(const short8*)(ar1 + kt * 64);
            m00 = __builtin_amdgcn_mfma_f32_16x16x32_bf16(a0, bfrag[kt][0], m00, 0, 0, 0);
            m01 = __builtin_amdgcn_mfma_f32_16x16x32_bf16(a0, bfrag[kt][1], m01, 0, 0, 0);
            m10 = __builtin_amdgcn_mfma_f32_16x16x32_bf16(a1, bfrag[kt][0], m10, 0, 0, 0);
            m11 = __builtin_amdgcn_mfma_f32_16x16x32_bf16(a1, bfrag[kt][1], m11, 0, 0, 0);
        }
        // epilogue: h = relu(E + T), sum over valid rows (C row = q*4+j)
        int rb0 = c * 64 + rt * 32 + q * 4;
        int rb1 = rb0 + 16;
#pragma unroll
        for (int j = 0; j < 4; j++) {
            if (rb0 + j < cnt) {
                asum0 += fmaxf(m00[j] + tv0[j][0], 0.f);
                asum1 += fmaxf(m01[j] + tv0[j][1], 0.f);
            }
            if (rb1 + j < cnt) {
                asum0 += fmaxf(m10[j] + tv1[j][0], 0.f);
                asum1 += fmaxf(m11[j] + tv1[j][1], 0.f);
            }
        }
        // no trailing barrier: next iter writes the OTHER buffer; its top barrier
        // orders this iter's reads before any overwrite.
    }

    // reduce across quads (same col in lanes l, l^16, l^32, l^48)
    asum0 += __shfl_xor(asum0, 16, 64);
    asum0 += __shfl_xor(asum0, 32, 64);
    asum1 += __shfl_xor(asum1, 16, 64);
    asum1 += __shfl_xor(asum1, 32, 64);
    if (lane < 16) {
        atomicAdd(&segacc[cg * 32 + lane],      asum0);
        atomicAdd(&segacc[cg * 32 + 16 + lane], asum1);
    }
    __syncthreads();
    if (tid < D_DIM) ACC[g * D_DIM + tid] = segacc[tid];
}

// ---- out[s][d] = sum_k (ACC[2s][k]+ACC[2s+1][k]) * W2[d][k] + cnt[s]*b2[d] ----
__global__ void k_out(const float* __restrict__ ACC, const float* __restrict__ W2,
                      const float* __restrict__ b2, const int* __restrict__ count,
                      float* __restrict__ out) {
    __shared__ float a[D_DIM];
    int s = blockIdx.x, d = threadIdx.x;
    a[d] = ACC[(2 * s) * D_DIM + d] + ACC[(2 * s + 1) * D_DIM + d];
    __syncthreads();
    float sum = (float)count[s] * b2[d];
    const float4* w = (const float4*)(W2 + d * D_DIM);
#pragma unroll
    for (int k = 0; k < 32; k++) {
        float4 wv = w[k];
        sum += a[4 * k + 0] * wv.x + a[4 * k + 1] * wv.y
             + a[4 * k + 2] * wv.z + a[4 * k + 3] * wv.w;
    }
    out[s * D_DIM + d] = sum;
}

extern "C" void kernel_launch(void* const* d_in, const int* in_sizes, int n_in,
                              void* d_out, int out_size, void* d_ws, size_t ws_size,
                              hipStream_t stream) {
    const float* embs = (const float*)d_in[0];
    const float* W1   = (const float*)d_in[1];
    const float* b1   = (const float*)d_in[2];
    const float* W2   = (const float*)d_in[3];
    const float* b2   = (const float*)d_in[4];
    const int*   bidx = (const int*)d_in[5];

    char* ws = (char*)d_ws;
    unsigned* w1bf_u = (unsigned*)(ws + WS_W1BF);
    short*    w1bf   = (short*)(ws + WS_W1BF);
    int*   count  = (int*)(ws + WS_COUNT);
    float* T      = (float*)(ws + WS_T);
    float* ACC    = (float*)(ws + WS_ACC);
    int*   P      = (int*)(ws + WS_P);

    hipMemsetAsync(count, 0, 256 * sizeof(int), stream);
    k_prep<<<832, 256, 0, stream>>>(W1, w1bf_u, bidx, count, P, embs, b1, T);
    k_main<<<512, 512, 0, stream>>>(embs, T, w1bf, P, count, ACC);
    k_out<<<256, 128, 0, stream>>>(ACC, W2, b2, count, (float*)d_out);
}